// Round 3
// baseline (554.262 us; speedup 1.0000x reference)
//
#include <hip/hip_runtime.h>

#define D 64

// ---------------- setup kernels ----------------

__global__ void hist_kernel(const int* __restrict__ src, const int* __restrict__ dst,
                            int* __restrict__ deg_src, int* __restrict__ deg_dst, int E) {
    int i = blockIdx.x * blockDim.x + threadIdx.x;
    if (i < E) {
        atomicAdd(&deg_src[src[i]], 1);
        atomicAdd(&deg_dst[dst[i]], 1);
    }
}

// Scan step 1: per-block (1024 elements) totals of deg_dst.
__global__ void scan1_kernel(const int* __restrict__ deg, int* __restrict__ blk_tot, int n) {
    __shared__ int sdata[256];
    int tid = threadIdx.x;
    int base = blockIdx.x * 1024 + tid * 4;
    int s = 0;
#pragma unroll
    for (int j = 0; j < 4; j++) {
        int idx = base + j;
        s += (idx < n) ? deg[idx] : 0;
    }
    sdata[tid] = s;
    __syncthreads();
    for (int off = 128; off > 0; off >>= 1) {
        if (tid < off) sdata[tid] += sdata[tid + off];
        __syncthreads();
    }
    if (tid == 0) blk_tot[blockIdx.x] = sdata[0];
}

// Scan step 2: exclusive scan of block totals (single block, nb <= 1024).
__global__ void scan2_kernel(int* __restrict__ blk_tot, int nb) {
    __shared__ int tmp[1024];
    int tid = threadIdx.x;
    int v = (tid < nb) ? blk_tot[tid] : 0;
    tmp[tid] = v;
    __syncthreads();
    int val = v;
    for (int off = 1; off < 1024; off <<= 1) {
        int add = (tid >= off) ? tmp[tid - off] : 0;
        __syncthreads();
        val += add;
        tmp[tid] = val;
        __syncthreads();
    }
    if (tid < nb) blk_tot[tid] = val - v;  // exclusive
}

// Scan step 3: write exclusive row_ptr, plus both degree norms (fused).
__global__ void scan3_norms_kernel(const int* __restrict__ deg_dst, const int* __restrict__ deg_src,
                                   const int* __restrict__ blk_tot, int* __restrict__ row_ptr,
                                   float* __restrict__ out_norm, float* __restrict__ in_norm,
                                   int n, int E) {
    __shared__ int sdata[256];
    int tid = threadIdx.x;
    int base = blockIdx.x * 1024 + tid * 4;
    int v[4];
    int s = 0;
#pragma unroll
    for (int j = 0; j < 4; j++) {
        int idx = base + j;
        v[j] = (idx < n) ? deg_dst[idx] : 0;
        s += v[j];
    }
    sdata[tid] = s;
    __syncthreads();
    int val = s;
    for (int off = 1; off < 256; off <<= 1) {
        int add = (tid >= off) ? sdata[tid - off] : 0;
        __syncthreads();
        val += add;
        sdata[tid] = val;
        __syncthreads();
    }
    int excl = blk_tot[blockIdx.x] + val - s;
#pragma unroll
    for (int j = 0; j < 4; j++) {
        int idx = base + j;
        if (idx < n) {
            row_ptr[idx] = excl;
            in_norm[idx] = rsqrtf((float)max(v[j], 1));
            out_norm[idx] = rsqrtf((float)max(deg_src[idx], 1));
        }
        excl += v[j];
    }
    if (blockIdx.x == 0 && tid == 0) row_ptr[n] = E;
}

// Reuses deg_dst as a countdown (atomicSub) so no separate cnt array/memset.
__global__ void fill_csr_kernel(const int* __restrict__ src, const int* __restrict__ dst,
                                const int* __restrict__ row_ptr, int* __restrict__ deg_cnt,
                                int* __restrict__ csr_src, int E) {
    int i = blockIdx.x * blockDim.x + threadIdx.x;
    if (i < E) {
        int d = dst[i];
        int slot = atomicSub(&deg_cnt[d], 1) - 1;  // unique slot in [0, deg)
        csr_src[row_ptr[d] + slot] = src[i];
    }
}

// ---------------- dense GEMM: Y[row] = (X[row] @ W) * (scale ? out_norm[row] : 1) ----------
// Wave handles 16 consecutive rows. W column held in 64 VGPRs (one column element
// per k, lane = output column j), loaded ONCE per wave. X row is wave-uniform ->
// forced through readfirstlane so the compiler emits scalar (s_load) reads; each
// MAC is then a single v_fmac_f32 v, s, v.
__global__ __launch_bounds__(256) void gemm_kernel(
    const float* __restrict__ X, const float* __restrict__ W,
    const float* __restrict__ out_norm, float* __restrict__ Y,
    int n, int scale_rows) {
    int lane = threadIdx.x & 63;
    int wid = blockIdx.x * 4 + (threadIdx.x >> 6);
    int base = wid * 16;
    if (base >= n) return;

    float w[D];
#pragma unroll
    for (int k = 0; k < D; k++) w[k] = W[k * D + lane];

    int m = min(16, n - base);
    for (int i = 0; i < m; i++) {
        int row = base + i;
        const float* Xr = X + (size_t)__builtin_amdgcn_readfirstlane(row) * D;
        float o0 = 0.f, o1 = 0.f, o2 = 0.f, o3 = 0.f;
#pragma unroll
        for (int k = 0; k < D; k += 4) {
            o0 = fmaf(Xr[k + 0], w[k + 0], o0);
            o1 = fmaf(Xr[k + 1], w[k + 1], o1);
            o2 = fmaf(Xr[k + 2], w[k + 2], o2);
            o3 = fmaf(Xr[k + 3], w[k + 3], o3);
        }
        float o = (o0 + o1) + (o2 + o3);
        if (scale_rows) o *= out_norm[row];
        Y[(size_t)row * D + lane] = o;
    }
}

// ---------------- gather-sum: h[v] = post( in_norm[v] * sum_{e} P[src(e)] + b ) ----------
// Wave per node. 4 edge-groups x 16 feature-lanes, float4/lane. No W, no GEMM:
// minimal VALU, small VGPR footprint -> high occupancy, latency-tolerant.
__global__ __launch_bounds__(256) void gather_kernel(
    const float4* __restrict__ P4, const int* __restrict__ csr_src,
    const int* __restrict__ row_ptr, const float* __restrict__ in_norm,
    const float* __restrict__ out_norm, const float* __restrict__ bias,
    float4* __restrict__ out4, int n, int relu_scale) {
    int tid = threadIdx.x;
    int lane = tid & 63;
    int v = blockIdx.x * 4 + (tid >> 6);
    if (v >= n) return;

    int begin = row_ptr[v];
    int end = row_ptr[v + 1];
    int eg = lane >> 4;   // edge group 0..3
    int fl = lane & 15;   // float4 index within row

    float4 acc = make_float4(0.f, 0.f, 0.f, 0.f);
    float4 acc2 = make_float4(0.f, 0.f, 0.f, 0.f);
    int e = begin + eg;
    // 2-deep: keep two independent feature loads in flight
    for (; e + 4 < end; e += 8) {
        int s0 = csr_src[e];
        int s1 = csr_src[e + 4];
        float4 a = P4[(size_t)s0 * 16 + fl];
        float4 b = P4[(size_t)s1 * 16 + fl];
        acc.x += a.x; acc.y += a.y; acc.z += a.z; acc.w += a.w;
        acc2.x += b.x; acc2.y += b.y; acc2.z += b.z; acc2.w += b.w;
    }
    if (e < end) {
        int s = csr_src[e];
        float4 a = P4[(size_t)s * 16 + fl];
        acc.x += a.x; acc.y += a.y; acc.z += a.z; acc.w += a.w;
    }
    acc.x += acc2.x; acc.y += acc2.y; acc.z += acc2.z; acc.w += acc2.w;

    // reduce 4 edge groups -> lanes 0..15 hold full sums
    acc.x += __shfl_down(acc.x, 32); acc.y += __shfl_down(acc.y, 32);
    acc.z += __shfl_down(acc.z, 32); acc.w += __shfl_down(acc.w, 32);
    acc.x += __shfl_down(acc.x, 16); acc.y += __shfl_down(acc.y, 16);
    acc.z += __shfl_down(acc.z, 16); acc.w += __shfl_down(acc.w, 16);

    if (eg == 0) {
        float inv = in_norm[v];
        float4 b4 = ((const float4*)bias)[fl];
        float4 o;
        o.x = fmaf(acc.x, inv, b4.x);
        o.y = fmaf(acc.y, inv, b4.y);
        o.z = fmaf(acc.z, inv, b4.z);
        o.w = fmaf(acc.w, inv, b4.w);
        if (relu_scale) {
            float sc = out_norm[v];
            o.x = fmaxf(o.x, 0.f) * sc;
            o.y = fmaxf(o.y, 0.f) * sc;
            o.z = fmaxf(o.z, 0.f) * sc;
            o.w = fmaxf(o.w, 0.f) * sc;
        }
        out4[(size_t)v * 16 + fl] = o;
    }
}

// ---------------- launch ----------------

extern "C" void kernel_launch(void* const* d_in, const int* in_sizes, int n_in,
                              void* d_out, int out_size, void* d_ws, size_t ws_size,
                              hipStream_t stream) {
    const float* x  = (const float*)d_in[0];
    const int* src  = (const int*)d_in[1];
    const int* dst  = (const int*)d_in[2];
    const float* W1 = (const float*)d_in[3];
    const float* b1 = (const float*)d_in[4];
    const float* W2 = (const float*)d_in[5];
    const float* b2 = (const float*)d_in[6];
    const float* W3 = (const float*)d_in[7];
    const float* b3 = (const float*)d_in[8];

    const int N = in_sizes[0] / D;
    const int E = in_sizes[1];

    char* ws = (char*)d_ws;
    size_t off = 0;
    auto alloc = [&](size_t elems) -> void* {
        void* p = (void*)(ws + off);
        off += ((elems + 3) / 4) * 16;  // pad to 16B
        return p;
    };
    int* deg_src   = (int*)alloc(N);   // contiguous with deg_dst for one memset
    int* deg_dst   = (int*)alloc(N);
    int* row_ptr   = (int*)alloc(N + 1);
    int* blk_tot   = (int*)alloc(1024);
    float* out_nrm = (float*)alloc(N);
    float* in_nrm  = (float*)alloc(N);
    int* csr_src   = (int*)alloc(E);
    float* bufP    = (float*)alloc((size_t)N * D);  // transformed+scaled features
    float* bufH    = (float*)alloc((size_t)N * D);  // hidden state

    const int B = 256;
    hipMemsetAsync(deg_src, 0, (size_t)2 * N * sizeof(int), stream);
    hist_kernel<<<(E + B - 1) / B, B, 0, stream>>>(src, dst, deg_src, deg_dst, E);

    int nb = (N + 1023) / 1024;
    scan1_kernel<<<nb, 256, 0, stream>>>(deg_dst, blk_tot, N);
    scan2_kernel<<<1, 1024, 0, stream>>>(blk_tot, nb);
    scan3_norms_kernel<<<nb, 256, 0, stream>>>(deg_dst, deg_src, blk_tot, row_ptr,
                                               out_nrm, in_nrm, N, E);

    fill_csr_kernel<<<(E + B - 1) / B, B, 0, stream>>>(src, dst, row_ptr, deg_dst,
                                                       csr_src, E);

    int ggrid = (N / 16 + 3) / 4;           // 16 rows/wave, 4 waves/block
    int sgrid = (N + 3) / 4;                // 1 node/wave, 4 waves/block

    // layer 1: P = (X W1) * out_norm ; h1 = relu(in_norm*(A P) + b1) * out_norm
    gemm_kernel<<<ggrid, 256, 0, stream>>>(x, W1, out_nrm, bufP, N, 1);
    gather_kernel<<<sgrid, 256, 0, stream>>>((const float4*)bufP, csr_src, row_ptr,
                                             in_nrm, out_nrm, b1, (float4*)bufH, N, 1);
    // layer 2: h1 already carries out_norm; P = h1 W2
    gemm_kernel<<<ggrid, 256, 0, stream>>>(bufH, W2, out_nrm, bufP, N, 0);
    gather_kernel<<<sgrid, 256, 0, stream>>>((const float4*)bufP, csr_src, row_ptr,
                                             in_nrm, out_nrm, b2, (float4*)bufH, N, 1);
    // layer 3: final — no relu, no pre-scale
    gemm_kernel<<<ggrid, 256, 0, stream>>>(bufH, W3, out_nrm, bufP, N, 0);
    gather_kernel<<<sgrid, 256, 0, stream>>>((const float4*)bufP, csr_src, row_ptr,
                                             in_nrm, out_nrm, b3, (float4*)d_out, N, 0);
}

// Round 4
// 503.158 us; speedup vs baseline: 1.1016x; 1.1016x over previous
//
#include <hip/hip_runtime.h>

#define D 64

// ---------------- setup kernels ----------------

// Histogram of src and dst degrees; ALSO captures each edge's slot within its
// dst bucket from the atomicAdd return (we pay for the return anyway), so the
// CSR fill needs no atomics.
__global__ void hist_slot_kernel(const int* __restrict__ src, const int* __restrict__ dst,
                                 int* __restrict__ deg_src, int* __restrict__ deg_dst,
                                 int* __restrict__ slot, int E) {
    int i = blockIdx.x * blockDim.x + threadIdx.x;
    if (i < E) {
        atomicAdd(&deg_src[src[i]], 1);
        slot[i] = atomicAdd(&deg_dst[dst[i]], 1);
    }
}

// Scan step 1: per-block (1024 elements) totals of deg_dst.
__global__ void scan1_kernel(const int* __restrict__ deg, int* __restrict__ blk_tot, int n) {
    __shared__ int sdata[256];
    int tid = threadIdx.x;
    int base = blockIdx.x * 1024 + tid * 4;
    int s = 0;
#pragma unroll
    for (int j = 0; j < 4; j++) {
        int idx = base + j;
        s += (idx < n) ? deg[idx] : 0;
    }
    sdata[tid] = s;
    __syncthreads();
    for (int off = 128; off > 0; off >>= 1) {
        if (tid < off) sdata[tid] += sdata[tid + off];
        __syncthreads();
    }
    if (tid == 0) blk_tot[blockIdx.x] = sdata[0];
}

// Scan step 2: exclusive scan of block totals (single block, nb <= 1024).
__global__ void scan2_kernel(int* __restrict__ blk_tot, int nb) {
    __shared__ int tmp[1024];
    int tid = threadIdx.x;
    int v = (tid < nb) ? blk_tot[tid] : 0;
    tmp[tid] = v;
    __syncthreads();
    int val = v;
    for (int off = 1; off < 1024; off <<= 1) {
        int add = (tid >= off) ? tmp[tid - off] : 0;
        __syncthreads();
        val += add;
        tmp[tid] = val;
        __syncthreads();
    }
    if (tid < nb) blk_tot[tid] = val - v;  // exclusive
}

// Scan step 3: write exclusive row_ptr, plus both degree norms (fused).
__global__ void scan3_norms_kernel(const int* __restrict__ deg_dst, const int* __restrict__ deg_src,
                                   const int* __restrict__ blk_tot, int* __restrict__ row_ptr,
                                   float* __restrict__ out_norm, float* __restrict__ in_norm,
                                   int n, int E) {
    __shared__ int sdata[256];
    int tid = threadIdx.x;
    int base = blockIdx.x * 1024 + tid * 4;
    int v[4];
    int s = 0;
#pragma unroll
    for (int j = 0; j < 4; j++) {
        int idx = base + j;
        v[j] = (idx < n) ? deg_dst[idx] : 0;
        s += v[j];
    }
    sdata[tid] = s;
    __syncthreads();
    int val = s;
    for (int off = 1; off < 256; off <<= 1) {
        int add = (tid >= off) ? sdata[tid - off] : 0;
        __syncthreads();
        val += add;
        sdata[tid] = val;
        __syncthreads();
    }
    int excl = blk_tot[blockIdx.x] + val - s;
#pragma unroll
    for (int j = 0; j < 4; j++) {
        int idx = base + j;
        if (idx < n) {
            row_ptr[idx] = excl;
            in_norm[idx] = rsqrtf((float)max(v[j], 1));
            out_norm[idx] = rsqrtf((float)max(deg_src[idx], 1));
        }
        excl += v[j];
    }
    if (blockIdx.x == 0 && tid == 0) row_ptr[n] = E;
}

// Atomic-free CSR fill: slot was captured during the histogram.
__global__ void fill_csr_kernel(const int* __restrict__ src, const int* __restrict__ dst,
                                const int* __restrict__ row_ptr, const int* __restrict__ slot,
                                int* __restrict__ csr_src, int E) {
    int i = blockIdx.x * blockDim.x + threadIdx.x;
    if (i < E) {
        csr_src[row_ptr[dst[i]] + slot[i]] = src[i];
    }
}

// ---------------- dense GEMM: Y[row] = (X[row] @ W) * (scale ? out_norm[row] : 1) ----------
// Wave handles 16 consecutive rows. W column in 64 VGPRs (loaded once); X row is
// wave-uniform -> readfirstlane forces scalar loads; each MAC is v_fmac v,s,v.
__global__ __launch_bounds__(256) void gemm_kernel(
    const float* __restrict__ X, const float* __restrict__ W,
    const float* __restrict__ out_norm, float* __restrict__ Y,
    int n, int scale_rows) {
    int lane = threadIdx.x & 63;
    int wid = blockIdx.x * 4 + (threadIdx.x >> 6);
    int base = wid * 16;
    if (base >= n) return;

    float w[D];
#pragma unroll
    for (int k = 0; k < D; k++) w[k] = W[k * D + lane];

    int m = min(16, n - base);
    for (int i = 0; i < m; i++) {
        int row = base + i;
        const float* Xr = X + (size_t)__builtin_amdgcn_readfirstlane(row) * D;
        float o0 = 0.f, o1 = 0.f, o2 = 0.f, o3 = 0.f;
#pragma unroll
        for (int k = 0; k < D; k += 4) {
            o0 = fmaf(Xr[k + 0], w[k + 0], o0);
            o1 = fmaf(Xr[k + 1], w[k + 1], o1);
            o2 = fmaf(Xr[k + 2], w[k + 2], o2);
            o3 = fmaf(Xr[k + 3], w[k + 3], o3);
        }
        float o = (o0 + o1) + (o2 + o3);
        if (scale_rows) o *= out_norm[row];
        Y[(size_t)row * D + lane] = o;
    }
}

// ---------------- gather-sum: h[v] = post( in_norm[v] * sum_{e} P[src(e)] + b ) ----------
// Wave per node. 4 edge-groups x 16 feature-lanes, float4/lane. 16-edge chunks:
// 4 independent index loads -> up to 4 independent row loads, per-lane exec
// masking (no wasted traffic). Avg degree 10 => one chunk covers most nodes:
// 2 serialized memory latencies per node instead of a dependent chain.
__global__ __launch_bounds__(256) void gather_kernel(
    const float4* __restrict__ P4, const int* __restrict__ csr_src,
    const int* __restrict__ row_ptr, const float* __restrict__ in_norm,
    const float* __restrict__ out_norm, const float* __restrict__ bias,
    float4* __restrict__ out4, int n, int relu_scale) {
    int tid = threadIdx.x;
    int lane = tid & 63;
    int v = blockIdx.x * 4 + (tid >> 6);
    if (v >= n) return;

    int begin = row_ptr[v];
    int end = row_ptr[v + 1];
    int eg = lane >> 4;   // edge group 0..3
    int fl = lane & 15;   // float4 index within row

    // hoist epilogue operands above the gather loop
    float inv = in_norm[v];
    float sc = relu_scale ? out_norm[v] : 1.f;
    float4 b4 = ((const float4*)bias)[fl];

    float4 acc0 = make_float4(0.f, 0.f, 0.f, 0.f);
    float4 acc1 = make_float4(0.f, 0.f, 0.f, 0.f);

    for (int base_e = begin; base_e < end; base_e += 16) {
        int e0 = base_e + eg;
        int e1 = e0 + 4;
        int e2 = e0 + 8;
        int e3 = e0 + 12;
        // independent index loads (group-uniform addresses broadcast in HW)
        int j0 = (e0 < end) ? csr_src[e0] : -1;
        int j1 = (e1 < end) ? csr_src[e1] : -1;
        int j2 = (e2 < end) ? csr_src[e2] : -1;
        int j3 = (e3 < end) ? csr_src[e3] : -1;
        // independent row loads, exec-masked per lane
        if (j0 >= 0) {
            float4 a = P4[(size_t)j0 * 16 + fl];
            acc0.x += a.x; acc0.y += a.y; acc0.z += a.z; acc0.w += a.w;
        }
        if (j1 >= 0) {
            float4 a = P4[(size_t)j1 * 16 + fl];
            acc1.x += a.x; acc1.y += a.y; acc1.z += a.z; acc1.w += a.w;
        }
        if (j2 >= 0) {
            float4 a = P4[(size_t)j2 * 16 + fl];
            acc0.x += a.x; acc0.y += a.y; acc0.z += a.z; acc0.w += a.w;
        }
        if (j3 >= 0) {
            float4 a = P4[(size_t)j3 * 16 + fl];
            acc1.x += a.x; acc1.y += a.y; acc1.z += a.z; acc1.w += a.w;
        }
    }
    acc0.x += acc1.x; acc0.y += acc1.y; acc0.z += acc1.z; acc0.w += acc1.w;

    // reduce 4 edge groups -> lanes 0..15 hold full sums
    acc0.x += __shfl_down(acc0.x, 32); acc0.y += __shfl_down(acc0.y, 32);
    acc0.z += __shfl_down(acc0.z, 32); acc0.w += __shfl_down(acc0.w, 32);
    acc0.x += __shfl_down(acc0.x, 16); acc0.y += __shfl_down(acc0.y, 16);
    acc0.z += __shfl_down(acc0.z, 16); acc0.w += __shfl_down(acc0.w, 16);

    if (eg == 0) {
        float4 o;
        o.x = fmaf(acc0.x, inv, b4.x);
        o.y = fmaf(acc0.y, inv, b4.y);
        o.z = fmaf(acc0.z, inv, b4.z);
        o.w = fmaf(acc0.w, inv, b4.w);
        if (relu_scale) {
            o.x = fmaxf(o.x, 0.f) * sc;
            o.y = fmaxf(o.y, 0.f) * sc;
            o.z = fmaxf(o.z, 0.f) * sc;
            o.w = fmaxf(o.w, 0.f) * sc;
        }
        out4[(size_t)v * 16 + fl] = o;
    }
}

// ---------------- launch ----------------

extern "C" void kernel_launch(void* const* d_in, const int* in_sizes, int n_in,
                              void* d_out, int out_size, void* d_ws, size_t ws_size,
                              hipStream_t stream) {
    const float* x  = (const float*)d_in[0];
    const int* src  = (const int*)d_in[1];
    const int* dst  = (const int*)d_in[2];
    const float* W1 = (const float*)d_in[3];
    const float* b1 = (const float*)d_in[4];
    const float* W2 = (const float*)d_in[5];
    const float* b2 = (const float*)d_in[6];
    const float* W3 = (const float*)d_in[7];
    const float* b3 = (const float*)d_in[8];

    const int N = in_sizes[0] / D;
    const int E = in_sizes[1];

    char* ws = (char*)d_ws;
    size_t off = 0;
    auto alloc = [&](size_t elems) -> void* {
        void* p = (void*)(ws + off);
        off += ((elems + 3) / 4) * 16;  // pad to 16B
        return p;
    };
    int* deg_src   = (int*)alloc(N);   // contiguous with deg_dst for one memset
    int* deg_dst   = (int*)alloc(N);
    int* row_ptr   = (int*)alloc(N + 1);
    int* blk_tot   = (int*)alloc(1024);
    float* out_nrm = (float*)alloc(N);
    float* in_nrm  = (float*)alloc(N);
    int* slot      = (int*)alloc(E);
    int* csr_src   = (int*)alloc(E);
    float* bufP    = (float*)alloc((size_t)N * D);  // transformed+scaled features
    float* bufH    = (float*)alloc((size_t)N * D);  // hidden state

    const int B = 256;
    hipMemsetAsync(deg_src, 0, (size_t)2 * N * sizeof(int), stream);
    hist_slot_kernel<<<(E + B - 1) / B, B, 0, stream>>>(src, dst, deg_src, deg_dst,
                                                        slot, E);

    int nb = (N + 1023) / 1024;
    scan1_kernel<<<nb, 256, 0, stream>>>(deg_dst, blk_tot, N);
    scan2_kernel<<<1, 1024, 0, stream>>>(blk_tot, nb);
    scan3_norms_kernel<<<nb, 256, 0, stream>>>(deg_dst, deg_src, blk_tot, row_ptr,
                                               out_nrm, in_nrm, N, E);

    fill_csr_kernel<<<(E + B - 1) / B, B, 0, stream>>>(src, dst, row_ptr, slot,
                                                       csr_src, E);

    int ggrid = (N / 16 + 3) / 4;           // 16 rows/wave, 4 waves/block
    int sgrid = (N + 3) / 4;                // 1 node/wave, 4 waves/block

    // layer 1: P = (X W1) * out_norm ; h1 = relu(in_norm*(A P) + b1) * out_norm
    gemm_kernel<<<ggrid, 256, 0, stream>>>(x, W1, out_nrm, bufP, N, 1);
    gather_kernel<<<sgrid, 256, 0, stream>>>((const float4*)bufP, csr_src, row_ptr,
                                             in_nrm, out_nrm, b1, (float4*)bufH, N, 1);
    // layer 2: h1 already carries out_norm; P = h1 W2
    gemm_kernel<<<ggrid, 256, 0, stream>>>(bufH, W2, out_nrm, bufP, N, 0);
    gather_kernel<<<sgrid, 256, 0, stream>>>((const float4*)bufP, csr_src, row_ptr,
                                             in_nrm, out_nrm, b2, (float4*)bufH, N, 1);
    // layer 3: final — no relu, no pre-scale
    gemm_kernel<<<ggrid, 256, 0, stream>>>(bufH, W3, out_nrm, bufP, N, 0);
    gather_kernel<<<sgrid, 256, 0, stream>>>((const float4*)bufP, csr_src, row_ptr,
                                             in_nrm, out_nrm, b3, (float4*)d_out, N, 0);
}